// Round 2
// baseline (654.336 us; speedup 1.0000x reference)
//
#include <hip/hip_runtime.h>
#include <type_traits>

// ---------- types ----------
typedef __bf16 bf16;
typedef __bf16 bf16x8 __attribute__((ext_vector_type(8)));
typedef float  f32x4  __attribute__((ext_vector_type(4)));

// B=2, N=2048, QN=512, LN=256, D=1024, QD=1024, LD=64, H=QH=16, HD=QHD=64
// All inputs/outputs fp32 (reference dtype). MFMA internally in bf16.

// ---------------------------------------------------------------------------
// GEMM: C = A[M,K] @ B[K,N] (+bias). A is fp32 or bf16 (template), B fp32.
// Tile 64x64, BK=32, 4 waves (each a 32x32 quadrant of 2x2 16x16x32 MFMAs).
// Verified layouts:
//   A-frag: A[m = lane&15][k = (lane>>4)*8 + j]
//   B-frag: B[k = (lane>>4)*8 + j][n = lane&15]   (stage B transposed)
//   C/D:    row = (lane>>4)*4 + reg, col = lane&15
// SPLIT epilogue scatters col blocks of 1024 into per-head [B*16][ntok][64]
// buffers (fuses the qkv/kv/qqkv reshape+transpose).
// ---------------------------------------------------------------------------
template <typename AT, typename OT, bool SPLIT>
__global__ __launch_bounds__(256) void gemm_kernel(
    const AT* __restrict__ A, const float* __restrict__ B,
    OT* __restrict__ C0, OT* __restrict__ C1, OT* __restrict__ C2,
    const float* __restrict__ bias, int M, int N, int K, int tshift)
{
    __shared__ __align__(16) bf16 As[64][40];   // [m][k]
    __shared__ __align__(16) bf16 Bs[64][40];   // transposed: [n][k]

    const int tid  = threadIdx.x;
    const int wave = tid >> 6, lane = tid & 63;
    const int l15  = lane & 15;
    const int q8   = (lane >> 4) << 3;
    const int q4   = (lane >> 4) << 2;
    const int m0   = blockIdx.y << 6, n0 = blockIdx.x << 6;
    const int rw   = (wave & 1) << 5, cw = (wave >> 1) << 5;
    const int arow = tid >> 2, acol = (tid & 3) << 3;   // A: 64x32, 8/thread
    const int brow = tid >> 3, bcol = (tid & 7) << 3;   // B: 32x64, 8/thread

    f32x4 acc[2][2] = {};

    for (int k0 = 0; k0 < K; k0 += 32) {
        __syncthreads();
        bf16x8 av;
        if constexpr (std::is_same_v<AT, float>) {
            f32x4 a0 = *(const f32x4*)(A + (size_t)(m0 + arow) * K + k0 + acol);
            f32x4 a1 = *(const f32x4*)(A + (size_t)(m0 + arow) * K + k0 + acol + 4);
#pragma unroll
            for (int j = 0; j < 4; j++) { av[j] = (bf16)a0[j]; av[4 + j] = (bf16)a1[j]; }
        } else {
            av = *(const bf16x8*)(A + (size_t)(m0 + arow) * K + k0 + acol);
        }
        *(bf16x8*)&As[arow][acol] = av;

        f32x4 b0 = *(const f32x4*)(B + (size_t)(k0 + brow) * N + n0 + bcol);
        f32x4 b1 = *(const f32x4*)(B + (size_t)(k0 + brow) * N + n0 + bcol + 4);
#pragma unroll
        for (int j = 0; j < 4; j++) {
            Bs[bcol + j][brow]     = (bf16)b0[j];
            Bs[bcol + 4 + j][brow] = (bf16)b1[j];
        }
        __syncthreads();

        bf16x8 a0 = *(const bf16x8*)&As[rw + l15][q8];
        bf16x8 a1 = *(const bf16x8*)&As[rw + 16 + l15][q8];
        bf16x8 bb0 = *(const bf16x8*)&Bs[cw + l15][q8];
        bf16x8 bb1 = *(const bf16x8*)&Bs[cw + 16 + l15][q8];
        acc[0][0] = __builtin_amdgcn_mfma_f32_16x16x32_bf16(a0, bb0, acc[0][0], 0, 0, 0);
        acc[0][1] = __builtin_amdgcn_mfma_f32_16x16x32_bf16(a0, bb1, acc[0][1], 0, 0, 0);
        acc[1][0] = __builtin_amdgcn_mfma_f32_16x16x32_bf16(a1, bb0, acc[1][0], 0, 0, 0);
        acc[1][1] = __builtin_amdgcn_mfma_f32_16x16x32_bf16(a1, bb1, acc[1][1], 0, 0, 0);
    }

    const int ntok = 1 << tshift;
#pragma unroll
    for (int rb = 0; rb < 2; rb++)
#pragma unroll
        for (int cb = 0; cb < 2; cb++) {
            int n = n0 + cw + (cb << 4) + l15;
            float bi = bias ? bias[n] : 0.0f;
#pragma unroll
            for (int r = 0; r < 4; r++) {
                int m = m0 + rw + (rb << 4) + q4 + r;
                float val = acc[rb][cb][r] + bi;
                if constexpr (SPLIT) {
                    int s = n >> 10, h = (n >> 6) & 15, hd = n & 63;
                    int b = m >> tshift, t = m & (ntok - 1);
                    OT* dst = (s == 0) ? C0 : (s == 1) ? C1 : C2;
                    dst[(((size_t)(((b << 4) + h) * ntok + t)) << 6) + hd] = (OT)val;
                } else {
                    C0[(size_t)m * N + n] = (OT)val;
                }
            }
        }
}

// ---------------------------------------------------------------------------
// Flash attention: Q [BH][nq][64], K/V [BH][nk][64] bf16 -> O [B][nq][1024]
// (head-concat cols). WG = (64 q-rows, one bh); 4 waves, 16-row strips.
// Online softmax; P round-trips LDS (C-layout -> A-layout). Optional per-head
// tanh(gate) scale and accumulate-into-O.
// ---------------------------------------------------------------------------
__global__ __launch_bounds__(256) void flash_kernel(
    const bf16* __restrict__ Q, const bf16* __restrict__ K,
    const bf16* __restrict__ V, bf16* __restrict__ O,
    const float* __restrict__ gate, int nq, int nk, int accum, float scale)
{
    __shared__ __align__(16) bf16 Qs[64][72];
    __shared__ __align__(16) bf16 Ks[64][72];      // [key][hd]
    __shared__ __align__(16) bf16 Vs[64][72];      // transposed: [hd][key]
    __shared__ __align__(16) bf16 Ps[4][16][72];   // per-wave P strip [row][key]

    const int tid = threadIdx.x;
    const int wave = tid >> 6, lane = tid & 63;
    const int l15 = lane & 15, q8 = (lane >> 4) << 3, q4 = (lane >> 4) << 2;
    const int bh = blockIdx.y, h = bh & 15, b = bh >> 4;
    const int q0 = blockIdx.x << 6;
    const int myrow = wave << 4;

    const size_t qbase = (size_t)bh * nq * 64;
    const size_t kbase = (size_t)bh * nk * 64;

    {
        int r = tid >> 2, c = (tid & 3) << 4;
        const bf16* src = Q + qbase + (size_t)(q0 + r) * 64 + c;
        *(bf16x8*)&Qs[r][c]     = *(const bf16x8*)(src);
        *(bf16x8*)&Qs[r][c + 8] = *(const bf16x8*)(src + 8);
    }
    __syncthreads();
    bf16x8 qf0 = *(const bf16x8*)&Qs[myrow + l15][q8];
    bf16x8 qf1 = *(const bf16x8*)&Qs[myrow + l15][32 + q8];

    f32x4 Oacc[4] = {};
    float mrow[4], lrow[4];
#pragma unroll
    for (int r = 0; r < 4; r++) { mrow[r] = -1e30f; lrow[r] = 0.0f; }

    for (int k0 = 0; k0 < nk; k0 += 64) {
        __syncthreads();   // prior iter's K/V/P reads complete
        {
            int r = tid >> 2, c = (tid & 3) << 4;
            const bf16* ksrc = K + kbase + (size_t)(k0 + r) * 64 + c;
            *(bf16x8*)&Ks[r][c]     = *(const bf16x8*)(ksrc);
            *(bf16x8*)&Ks[r][c + 8] = *(const bf16x8*)(ksrc + 8);
            const bf16* vsrc = V + kbase + (size_t)(k0 + r) * 64 + c;
            bf16x8 v0 = *(const bf16x8*)(vsrc);
            bf16x8 v1 = *(const bf16x8*)(vsrc + 8);
#pragma unroll
            for (int j = 0; j < 8; j++) { Vs[c + j][r] = v0[j]; Vs[c + 8 + j][r] = v1[j]; }
        }
        __syncthreads();   // staging visible

        // S = scale * Q K^T (this wave's 16 rows x 64 keys)
        f32x4 S[4];
#pragma unroll
        for (int nb = 0; nb < 4; nb++) {
            bf16x8 kf0 = *(const bf16x8*)&Ks[(nb << 4) + l15][q8];
            bf16x8 kf1 = *(const bf16x8*)&Ks[(nb << 4) + l15][32 + q8];
            f32x4 s = {};
            s = __builtin_amdgcn_mfma_f32_16x16x32_bf16(qf0, kf0, s, 0, 0, 0);
            s = __builtin_amdgcn_mfma_f32_16x16x32_bf16(qf1, kf1, s, 0, 0, 0);
#pragma unroll
            for (int r = 0; r < 4; r++) s[r] *= scale;
            S[nb] = s;
        }

        // online softmax (row lives across the 16 lanes sharing lane>>4)
        float mnew[4], alpha[4], rsum[4];
#pragma unroll
        for (int r = 0; r < 4; r++) {
            float mx = fmaxf(fmaxf(S[0][r], S[1][r]), fmaxf(S[2][r], S[3][r]));
#pragma unroll
            for (int off = 1; off < 16; off <<= 1) mx = fmaxf(mx, __shfl_xor(mx, off));
            mnew[r] = fmaxf(mrow[r], mx);
            alpha[r] = __expf(mrow[r] - mnew[r]);
            mrow[r] = mnew[r];
            rsum[r] = 0.0f;
        }
#pragma unroll
        for (int nb = 0; nb < 4; nb++)
#pragma unroll
            for (int r = 0; r < 4; r++) {
                float p = __expf(S[nb][r] - mnew[r]);
                rsum[r] += p;
                Ps[wave][q4 + r][(nb << 4) + l15] = (bf16)p;
            }
#pragma unroll
        for (int r = 0; r < 4; r++) {
            float s = rsum[r];
#pragma unroll
            for (int off = 1; off < 16; off <<= 1) s += __shfl_xor(s, off);
            lrow[r] = lrow[r] * alpha[r] + s;
#pragma unroll
            for (int nb = 0; nb < 4; nb++) Oacc[nb][r] *= alpha[r];
        }
        __syncthreads();   // P visible

        // O += P @ V
        bf16x8 pf0 = *(const bf16x8*)&Ps[wave][l15][q8];
        bf16x8 pf1 = *(const bf16x8*)&Ps[wave][l15][32 + q8];
#pragma unroll
        for (int nb = 0; nb < 4; nb++) {
            bf16x8 vf0 = *(const bf16x8*)&Vs[(nb << 4) + l15][q8];
            bf16x8 vf1 = *(const bf16x8*)&Vs[(nb << 4) + l15][32 + q8];
            Oacc[nb] = __builtin_amdgcn_mfma_f32_16x16x32_bf16(pf0, vf0, Oacc[nb], 0, 0, 0);
            Oacc[nb] = __builtin_amdgcn_mfma_f32_16x16x32_bf16(pf1, vf1, Oacc[nb], 0, 0, 0);
        }
    }

    float g = gate ? tanhf(gate[h]) : 1.0f;
#pragma unroll
    for (int nb = 0; nb < 4; nb++)
#pragma unroll
        for (int r = 0; r < 4; r++) {
            int n = q0 + myrow + q4 + r;
            int col = (h << 6) + (nb << 4) + l15;
            size_t oidx = (((size_t)b * nq + n) << 10) + col;
            float val = Oacc[nb][r] / lrow[r] * g;
            if (accum) val += (float)O[oidx];
            O[oidx] = (bf16)val;
        }
}

// ---------------------------------------------------------------------------
// lr_out[b,i,j] = sum_k low_res[b, (i*64+k)&255, (i*64+k)>>8] * W[k,j] + b[j]
// (all fp32; tiny)
// ---------------------------------------------------------------------------
__global__ __launch_bounds__(256) void lr_kernel(
    const float* __restrict__ low_res, const float* __restrict__ W,
    const float* __restrict__ bias, float* __restrict__ out)
{
    int idx = blockIdx.x * 256 + threadIdx.x;   // 2*256*64 = 32768
    int j = idx & 63, i = (idx >> 6) & 255, b = idx >> 14;
    float acc = bias[j];
    const float* lr = low_res + ((size_t)b << 14);
    for (int k = 0; k < 64; k++) {
        int f = i * 64 + k;
        acc += lr[((f & 255) << 6) + (f >> 8)] * W[(k << 6) + j];
    }
    out[idx] = acc;
}

// ---------------------------------------------------------------------------
extern "C" void kernel_launch(void* const* d_in, const int* in_sizes, int n_in,
                              void* d_out, int out_size, void* d_ws, size_t ws_size,
                              hipStream_t stream)
{
    const float* x       = (const float*)d_in[0];
    const float* query   = (const float*)d_in[1];
    const float* lowres  = (const float*)d_in[2];
    const float* W_qkv   = (const float*)d_in[3];
    const float* W_xkv   = (const float*)d_in[4];
    const float* W_qlin  = (const float*)d_in[5];
    const float* gate    = (const float*)d_in[6];
    const float* W_proj  = (const float*)d_in[7];
    const float* b_proj  = (const float*)d_in[8];
    const float* W_qproj = (const float*)d_in[9];
    const float* b_qproj = (const float*)d_in[10];
    const float* W_lr    = (const float*)d_in[11];
    const float* b_lr    = (const float*)d_in[12];
    float* out = (float*)d_out;

    char* ws = (char*)d_ws;
    bf16* qb = (bf16*)ws; ws += 8388608;   // [B*16][2048][64] bf16
    bf16* kb = (bf16*)ws; ws += 8388608;
    bf16* vb = (bf16*)ws; ws += 8388608;
    bf16* k2 = (bf16*)ws; ws += 8388608;
    bf16* v2 = (bf16*)ws; ws += 8388608;
    bf16* qq = (bf16*)ws; ws += 2097152;   // [B*16][512][64]
    bf16* qk = (bf16*)ws; ws += 2097152;
    bf16* qv = (bf16*)ws; ws += 2097152;
    bf16* ax = (bf16*)ws; ws += 8388608;   // [B][2048][1024] bf16
    bf16* aq = (bf16*)ws; ws += 2097152;   // [B][512][1024] bf16

    // qkv = x @ W_qkv -> q,k,v   (scatter fused into epilogue)
    gemm_kernel<float, bf16, true><<<dim3(48, 64), 256, 0, stream>>>(
        x, W_qkv, qb, kb, vb, nullptr, 4096, 3072, 1024, 11);
    // kv = x @ W_xkv -> k2,v2
    gemm_kernel<float, bf16, true><<<dim3(32, 64), 256, 0, stream>>>(
        x, W_xkv, k2, v2, nullptr, nullptr, 4096, 2048, 1024, 11);
    // qqkv = query @ W_qlin -> qq,qk,qv
    gemm_kernel<float, bf16, true><<<dim3(48, 16), 256, 0, stream>>>(
        query, W_qlin, qq, qk, qv, nullptr, 1024, 3072, 1024, 9);

    // self-attention over x
    flash_kernel<<<dim3(32, 32), 256, 0, stream>>>(qb, kb, vb, ax, nullptr, 2048, 2048, 0, 0.125f);
    // cross-attention: query-segment softmax, then gated x-segment accumulated
    flash_kernel<<<dim3(8, 32), 256, 0, stream>>>(qq, qk, qv, aq, nullptr, 512, 512, 0, 0.125f);
    flash_kernel<<<dim3(8, 32), 256, 0, stream>>>(qq, k2, v2, aq, gate, 512, 2048, 1, 0.125f);

    // output projections (fp32 out)
    gemm_kernel<bf16, float, false><<<dim3(16, 64), 256, 0, stream>>>(
        ax, W_proj, out, nullptr, nullptr, b_proj, 4096, 1024, 1024, 0);
    gemm_kernel<bf16, float, false><<<dim3(16, 16), 256, 0, stream>>>(
        aq, W_qproj, out + 4194304, nullptr, nullptr, b_qproj, 1024, 1024, 1024, 0);
    // low-res scramble + proj
    lr_kernel<<<128, 256, 0, stream>>>(lowres, W_lr, b_lr, out + 5242880);

    (void)in_sizes; (void)n_in; (void)out_size; (void)ws_size;
}

// Round 3
// 406.816 us; speedup vs baseline: 1.6084x; 1.6084x over previous
//
#include <hip/hip_runtime.h>

typedef __bf16 bf16;
typedef __bf16 bf16x4 __attribute__((ext_vector_type(4)));
typedef __bf16 bf16x8 __attribute__((ext_vector_type(8)));
typedef float  f32x4  __attribute__((ext_vector_type(4)));

// B=2, N=2048, QN=512, D=QD=1024, H=QH=16, HD=64. fp32 in/out, bf16 MFMA.

#define AS1(p) ((const __attribute__((address_space(1))) void*)(p))
#define AS3(p) ((__attribute__((address_space(3))) void*)(p))
__device__ __forceinline__ void gl16(const void* g, void* l) {
    __builtin_amdgcn_global_load_lds(AS1(g), AS3(l), 16, 0, 0);
}

// ---------------------------------------------------------------------------
// fp32 -> bf16 cast for x and query (vectorized, exact-grid)
// ---------------------------------------------------------------------------
__global__ __launch_bounds__(256) void cast_bf16(
    const float* __restrict__ s0, bf16* __restrict__ d0, int n0,
    const float* __restrict__ s1, bf16* __restrict__ d1, int n1)
{
    int idx = (blockIdx.x * 256 + threadIdx.x) << 3;
    const float* s; bf16* d;
    if (idx < n0) { s = s0 + idx; d = d0 + idx; }
    else { int k = idx - n0; if (k >= n1) return; s = s1 + k; d = d1 + k; }
    f32x4 a = *(const f32x4*)s, c = *(const f32x4*)(s + 4);
    bf16x8 v;
#pragma unroll
    for (int j = 0; j < 4; j++) { v[j] = (bf16)a[j]; v[4 + j] = (bf16)c[j]; }
    *(bf16x8*)d = v;
}

// ---------------------------------------------------------------------------
// All 5 weight matrices [K=1024][N] fp32 -> bf16 transposed [N][1024].
// 64x64 tiles through LDS; coalesced both sides.
// col-tile boundaries (64-col units): qkv 48, xkv 80, qlin 128, proj 144, qproj 160
// ---------------------------------------------------------------------------
__global__ __launch_bounds__(256) void wtrans(
    const float* __restrict__ S0, bf16* __restrict__ D0,
    const float* __restrict__ S1, bf16* __restrict__ D1,
    const float* __restrict__ S2, bf16* __restrict__ D2,
    const float* __restrict__ S3, bf16* __restrict__ D3,
    const float* __restrict__ S4, bf16* __restrict__ D4)
{
    __shared__ float T[64][65];
    int gx = blockIdx.x, k0 = blockIdx.y << 6;
    const float* S; bf16* D; int N;
    if (gx < 48)       { S = S0; D = D0; N = 3072; }
    else if (gx < 80)  { S = S1; D = D1; N = 2048; gx -= 48; }
    else if (gx < 128) { S = S2; D = D2; N = 3072; gx -= 80; }
    else if (gx < 144) { S = S3; D = D3; N = 1024; gx -= 128; }
    else               { S = S4; D = D4; N = 1024; gx -= 144; }
    int n0 = gx << 6, tid = threadIdx.x;
#pragma unroll
    for (int rr = 0; rr < 4; rr++) {
        int row = (rr << 4) + (tid >> 4), col = (tid & 15) << 2;
        f32x4 v = *(const f32x4*)(S + (size_t)(k0 + row) * N + n0 + col);
#pragma unroll
        for (int j = 0; j < 4; j++) T[col + j][row] = v[j];
    }
    __syncthreads();
    {
        int n = tid >> 2, kc = (tid & 3) << 4;
        bf16x8 v0, v1;
#pragma unroll
        for (int j = 0; j < 8; j++) {
            v0[j] = (bf16)T[n][kc + j];
            v1[j] = (bf16)T[n][kc + 8 + j];
        }
        bf16* dp = D + (size_t)(n0 + n) * 1024 + k0 + kc;
        *(bf16x8*)dp = v0; *(bf16x8*)(dp + 8) = v1;
    }
}

// ---------------------------------------------------------------------------
// GEMM (m97-style): C[M,N] = A[M,K] @ Bt[N,K]^T, bf16 in, 128x128 tile, BK=64,
// global_load_lds staging with XOR-swizzled LDS (chunk c stored at c^(r&7)).
// 4 waves in 2x2; each wave 64x64 = 4x4 of 16x16x32 MFMAs.
// NSPLIT>0: epilogue scatters col-blocks of 1024 into per-head buffers
// [bh][ntok][64]; the LAST split (V) is written transposed [bh][64][ntok].
// ---------------------------------------------------------------------------
template <int NSPLIT, typename OT>
__global__ __launch_bounds__(256) void gemm_bt(
    const bf16* __restrict__ A, const bf16* __restrict__ Bt,
    OT* __restrict__ C0, OT* __restrict__ C1, OT* __restrict__ C2,
    const float* __restrict__ bias, int M, int N, int K, int tshift)
{
    __shared__ __align__(16) bf16 As[128 * 64];
    __shared__ __align__(16) bf16 Bs[128 * 64];

    const int tid = threadIdx.x;
    const int wave = tid >> 6, lane = tid & 63;
    const int l15 = lane & 15, g = lane >> 4;
    const int wr = wave & 1, wc = wave >> 1;
    const int m0 = blockIdx.y << 7, n0 = blockIdx.x << 7;

    int sr[4], sc[4];
#pragma unroll
    for (int i = 0; i < 4; i++) {
        int L = (i << 8) + tid;
        sr[i] = L >> 3;
        sc[i] = (L & 7) ^ (sr[i] & 7);
    }
    const int ldsbase = (tid & 192) << 4;   // wave*1024 bytes

    f32x4 acc[4][4] = {};

    for (int k0 = 0; k0 < K; k0 += 64) {
        __syncthreads();
#pragma unroll
        for (int i = 0; i < 4; i++) {
            gl16(A  + (size_t)(m0 + sr[i]) * K + k0 + (sc[i] << 3),
                 (char*)As + (i << 12) + ldsbase);
            gl16(Bt + (size_t)(n0 + sr[i]) * K + k0 + (sc[i] << 3),
                 (char*)Bs + (i << 12) + ldsbase);
        }
        __syncthreads();

#pragma unroll
        for (int ks = 0; ks < 2; ks++) {
            bf16x8 af[4], bq[4];
#pragma unroll
            for (int mb = 0; mb < 4; mb++) {
                int row = (wr << 6) + (mb << 4) + l15;
                af[mb] = *(const bf16x8*)((const char*)As + (row << 7)
                          + ((((ks << 2) + g) ^ (row & 7)) << 4));
            }
#pragma unroll
            for (int nb = 0; nb < 4; nb++) {
                int row = (wc << 6) + (nb << 4) + l15;
                bq[nb] = *(const bf16x8*)((const char*)Bs + (row << 7)
                          + ((((ks << 2) + g) ^ (row & 7)) << 4));
            }
#pragma unroll
            for (int mb = 0; mb < 4; mb++)
#pragma unroll
                for (int nb = 0; nb < 4; nb++)
                    acc[mb][nb] = __builtin_amdgcn_mfma_f32_16x16x32_bf16(
                        af[mb], bq[nb], acc[mb][nb], 0, 0, 0);
        }
    }

    const int ntok = 1 << tshift;
#pragma unroll
    for (int mb = 0; mb < 4; mb++)
#pragma unroll
        for (int nb = 0; nb < 4; nb++) {
            int n = n0 + (wc << 6) + (nb << 4) + l15;
            int mbase = m0 + (wr << 6) + (mb << 4) + (g << 2);
            if constexpr (NSPLIT == 0) {
                float bi = bias[n];
#pragma unroll
                for (int r = 0; r < 4; r++)
                    C0[(size_t)(mbase + r) * N + n] = (OT)(acc[mb][nb][r] + bi);
            } else {
                int s = n >> 10, h = (n >> 6) & 15, hd = n & 63;
                int b = mbase >> tshift, t = mbase & (ntok - 1);
                int bh = (b << 4) + h;
                OT* dst = (s == 0) ? C0 : (s == 1) ? C1 : C2;
                if (s == NSPLIT - 1) {    // V: transposed [bh][hd][ntok]
                    bf16x4 pv;
#pragma unroll
                    for (int r = 0; r < 4; r++) pv[r] = (bf16)acc[mb][nb][r];
                    *(bf16x4*)&dst[(((size_t)bh << 6) + hd) * ntok + t] = pv;
                } else {
#pragma unroll
                    for (int r = 0; r < 4; r++)
                        dst[(((size_t)bh * ntok + t + r) << 6) + hd] = (OT)acc[mb][nb][r];
                }
            }
        }
}

// ---------------------------------------------------------------------------
// Flash attention, S^T formulation. Q [bh][nq][64], K [bh][nk][64],
// Vt [bh][64][nk] (pre-transposed). Computes S^T = K Q^T (A=K, B=Q — both
// frags read straight), per-q softmax state is per-lane scalar (2 shuffles),
// O^T accumulated via A=Vt, B=P. Two segments (seg0 gated by tanh(gate[h]),
// seg1 plain) summed — implements the split-softmax cross attention; self-attn
// passes nk2=0. Epilogue transposes O^T->O through LDS for coalesced stores.
// ---------------------------------------------------------------------------
__global__ __launch_bounds__(256) void flash2(
    const bf16* __restrict__ Q,
    const bf16* __restrict__ K1, const bf16* __restrict__ V1t,
    const bf16* __restrict__ K2, const bf16* __restrict__ V2t,
    bf16* __restrict__ O, const float* __restrict__ gate,
    int nq, int nk1, int nk2)
{
    // Qs [64][64] swz @elem 0 | Ks @4096 | Vs @8192 | Ps [4][16][80] @12288
    __shared__ __align__(16) bf16 sm[12288 + 5120];

    const int tid = threadIdx.x;
    const int wave = tid >> 6, lane = tid & 63;
    const int l15 = lane & 15, g = lane >> 4;
    const int q8 = g << 3, q4 = g << 2;
    const int bh = blockIdx.y, h = bh & 15, b = bh >> 4;
    const int q0 = blockIdx.x << 6;

    bf16* Qs = sm;
    bf16* Ks = sm + 4096;
    bf16* Vs = sm + 8192;
    bf16* Ps = sm + 12288 + wave * 1280;
    const int wbase = (tid & 192) << 4;

    {
        const bf16* qb = Q + ((size_t)bh * nq + q0) * 64;
#pragma unroll
        for (int i = 0; i < 2; i++) {
            int L = (i << 8) + tid;
            int r = L >> 3, c = (L & 7) ^ (r & 7);
            gl16(qb + (r << 6) + (c << 3), (char*)Qs + (i << 12) + wbase);
        }
    }
    __syncthreads();

    bf16x8 qf[2];
#pragma unroll
    for (int ks = 0; ks < 2; ks++) {
        int row = (wave << 4) + l15;
        qf[ks] = *(const bf16x8*)((const char*)Qs + (row << 7)
                  + ((((ks << 2) + g) ^ (row & 7)) << 4));
    }

    const float sc2 = 0.125f * 1.44269504088896f;   // scale * log2(e)
    f32x4 Ofin[4] = {};
    const float gmul = gate ? tanhf(gate[h]) : 1.0f;

    for (int seg = 0; seg < 2; seg++) {
        const bf16* Kp = seg ? K2 : K1;
        const bf16* Vp = seg ? V2t : V1t;
        const int nk = seg ? nk2 : nk1;
        if (nk == 0) break;

        f32x4 Oacc[4] = {};
        float mcur = -1e30f, lcur = 0.0f;

        for (int k0 = 0; k0 < nk; k0 += 64) {
            __syncthreads();
            const bf16* kb = Kp + ((size_t)bh * nk + k0) * 64;
            const bf16* vb = Vp + ((size_t)bh << 6) * nk + k0;
#pragma unroll
            for (int i = 0; i < 2; i++) {
                int L = (i << 8) + tid;
                int r = L >> 3, c = (L & 7) ^ (r & 7);
                gl16(kb + (r << 6) + (c << 3),      (char*)Ks + (i << 12) + wbase);
                gl16(vb + (size_t)r * nk + (c << 3), (char*)Vs + (i << 12) + wbase);
            }
            __syncthreads();

            // S^T[key][q] for this wave's 16 q-cols
            f32x4 S[4];
#pragma unroll
            for (int nb = 0; nb < 4; nb++) {
                f32x4 s = {};
#pragma unroll
                for (int ks = 0; ks < 2; ks++) {
                    int row = (nb << 4) + l15;
                    bf16x8 kf = *(const bf16x8*)((const char*)Ks + (row << 7)
                                + ((((ks << 2) + g) ^ (row & 7)) << 4));
                    s = __builtin_amdgcn_mfma_f32_16x16x32_bf16(kf, qf[ks], s, 0, 0, 0);
                }
                S[nb] = s;
            }

            // online softmax in log2 domain; per-lane state (q = l15)
            float mt = -1e30f;
#pragma unroll
            for (int nb = 0; nb < 4; nb++)
#pragma unroll
                for (int r = 0; r < 4; r++) {
                    S[nb][r] *= sc2;
                    mt = fmaxf(mt, S[nb][r]);
                }
            mt = fmaxf(mt, __shfl_xor(mt, 16));
            mt = fmaxf(mt, __shfl_xor(mt, 32));
            float mnew = fmaxf(mcur, mt);
            float alpha = exp2f(mcur - mnew);
            mcur = mnew;
            float rs = 0.0f;
#pragma unroll
            for (int nb = 0; nb < 4; nb++) {
                bf16x4 pv;
#pragma unroll
                for (int r = 0; r < 4; r++) {
                    float p = exp2f(S[nb][r] - mnew);
                    rs += p;
                    pv[r] = (bf16)p;
                }
                *(bf16x4*)&Ps[l15 * 80 + (nb << 4) + q4] = pv;   // P[q][key]
            }
            rs += __shfl_xor(rs, 16);
            rs += __shfl_xor(rs, 32);
            lcur = lcur * alpha + rs;
#pragma unroll
            for (int hb = 0; hb < 4; hb++)
#pragma unroll
                for (int r = 0; r < 4; r++) Oacc[hb][r] *= alpha;

            // O^T += Vt @ P^T
#pragma unroll
            for (int ks = 0; ks < 2; ks++) {
                bf16x8 pf = *(const bf16x8*)&Ps[l15 * 80 + (ks << 5) + q8];
#pragma unroll
                for (int hb = 0; hb < 4; hb++) {
                    int row = (hb << 4) + l15;
                    bf16x8 vf = *(const bf16x8*)((const char*)Vs + (row << 7)
                                + ((((ks << 2) + g) ^ (row & 7)) << 4));
                    Oacc[hb] = __builtin_amdgcn_mfma_f32_16x16x32_bf16(vf, pf, Oacc[hb], 0, 0, 0);
                }
            }
        }

        float w = (seg ? 1.0f : gmul) / lcur;
#pragma unroll
        for (int hb = 0; hb < 4; hb++)
#pragma unroll
            for (int r = 0; r < 4; r++) Ofin[hb][r] += Oacc[hb][r] * w;
    }

    // epilogue: O^T (regs) -> LDS [hd][q] -> coalesced O[q][h*64+hd]
    __syncthreads();
    bf16* OB = sm;   // [64][72], overlays Qs/Ks (dead now)
#pragma unroll
    for (int hb = 0; hb < 4; hb++)
#pragma unroll
        for (int r = 0; r < 4; r++)
            OB[((hb << 4) + q4 + r) * 72 + (wave << 4) + l15] = (bf16)Ofin[hb][r];
    __syncthreads();
    {
        int q = tid >> 2, quarter = (tid & 3) << 4;
        bf16x8 o0, o1;
#pragma unroll
        for (int j = 0; j < 8; j++) {
            o0[j] = OB[(quarter + j) * 72 + q];
            o1[j] = OB[(quarter + 8 + j) * 72 + q];
        }
        bf16* op = O + (((size_t)b * nq + q0 + q) << 10) + (h << 6) + quarter;
        *(bf16x8*)op = o0;
        *(bf16x8*)(op + 8) = o1;
    }
}

// ---------------------------------------------------------------------------
// lr_out[b,i,j] = sum_k low_res[b,(i*64+k)&255,(i*64+k)>>8] * W[k,j] + bias[j]
// ---------------------------------------------------------------------------
__global__ __launch_bounds__(256) void lr_kernel(
    const float* __restrict__ low_res, const float* __restrict__ W,
    const float* __restrict__ bias, float* __restrict__ out)
{
    int idx = blockIdx.x * 256 + threadIdx.x;
    int j = idx & 63, i = (idx >> 6) & 255, b = idx >> 14;
    float acc = bias[j];
    const float* lr = low_res + ((size_t)b << 14);
    for (int k = 0; k < 64; k++) {
        int f = i * 64 + k;
        acc += lr[((f & 255) << 6) + (f >> 8)] * W[(k << 6) + j];
    }
    out[idx] = acc;
}

// ---------------------------------------------------------------------------
extern "C" void kernel_launch(void* const* d_in, const int* in_sizes, int n_in,
                              void* d_out, int out_size, void* d_ws, size_t ws_size,
                              hipStream_t stream)
{
    const float* x       = (const float*)d_in[0];
    const float* query   = (const float*)d_in[1];
    const float* lowres  = (const float*)d_in[2];
    const float* W_qkv   = (const float*)d_in[3];
    const float* W_xkv   = (const float*)d_in[4];
    const float* W_qlin  = (const float*)d_in[5];
    const float* gate    = (const float*)d_in[6];
    const float* W_proj  = (const float*)d_in[7];
    const float* b_proj  = (const float*)d_in[8];
    const float* W_qproj = (const float*)d_in[9];
    const float* b_qproj = (const float*)d_in[10];
    const float* W_lr    = (const float*)d_in[11];
    const float* b_lr    = (const float*)d_in[12];
    float* out = (float*)d_out;

    char* ws = (char*)d_ws;
    bf16* Wtqkv   = (bf16*)ws; ws += 6291456;
    bf16* Wtxkv   = (bf16*)ws; ws += 4194304;
    bf16* Wtqlin  = (bf16*)ws; ws += 6291456;
    bf16* Wtproj  = (bf16*)ws; ws += 2097152;
    bf16* Wtqproj = (bf16*)ws; ws += 2097152;
    bf16* xb      = (bf16*)ws; ws += 8388608;   // ax aliases (xb dead by then)
    bf16* qryb    = (bf16*)ws; ws += 2097152;   // aq aliases
    bf16* qb      = (bf16*)ws; ws += 8388608;
    bf16* kb      = (bf16*)ws; ws += 8388608;
    bf16* vbt     = (bf16*)ws; ws += 8388608;   // [bh][64][2048]
    bf16* k2      = (bf16*)ws; ws += 8388608;
    bf16* v2t     = (bf16*)ws; ws += 8388608;   // [bh][64][2048]
    bf16* qq      = (bf16*)ws; ws += 2097152;
    bf16* qk      = (bf16*)ws; ws += 2097152;
    bf16* qvt     = (bf16*)ws; ws += 2097152;   // [bh][64][512]
    bf16* ax = xb;
    bf16* aq = qryb;

    cast_bf16<<<2560, 256, 0, stream>>>(x, xb, 4194304, query, qryb, 1048576);
    wtrans<<<dim3(160, 16), 256, 0, stream>>>(W_qkv, Wtqkv, W_xkv, Wtxkv,
                                              W_qlin, Wtqlin, W_proj, Wtproj,
                                              W_qproj, Wtqproj);

    gemm_bt<3, bf16><<<dim3(24, 32), 256, 0, stream>>>(
        xb, Wtqkv, qb, kb, vbt, nullptr, 4096, 3072, 1024, 11);
    gemm_bt<2, bf16><<<dim3(16, 32), 256, 0, stream>>>(
        xb, Wtxkv, k2, v2t, nullptr, nullptr, 4096, 2048, 1024, 11);
    gemm_bt<3, bf16><<<dim3(24, 8), 256, 0, stream>>>(
        qryb, Wtqlin, qq, qk, qvt, nullptr, 1024, 3072, 1024, 9);

    flash2<<<dim3(32, 32), 256, 0, stream>>>(
        qb, kb, vbt, nullptr, nullptr, ax, nullptr, 2048, 2048, 0);
    flash2<<<dim3(8, 32), 256, 0, stream>>>(
        qq, k2, v2t, qk, qvt, aq, gate, 512, 2048, 512);

    gemm_bt<0, float><<<dim3(8, 32), 256, 0, stream>>>(
        ax, Wtproj, out, nullptr, nullptr, b_proj, 4096, 1024, 1024, 0);
    gemm_bt<0, float><<<dim3(8, 8), 256, 0, stream>>>(
        aq, Wtqproj, out + 4194304, nullptr, nullptr, b_qproj, 1024, 1024, 1024, 0);
    lr_kernel<<<128, 256, 0, stream>>>(lowres, W_lr, b_lr, out + 5242880);

    (void)in_sizes; (void)n_in; (void)out_size; (void)ws_size;
}

// Round 4
// 377.188 us; speedup vs baseline: 1.7348x; 1.0785x over previous
//
#include <hip/hip_runtime.h>

typedef __bf16 bf16;
typedef __bf16 bf16x4 __attribute__((ext_vector_type(4)));
typedef __bf16 bf16x8 __attribute__((ext_vector_type(8)));
typedef float  f32x4  __attribute__((ext_vector_type(4)));

// B=2, N=2048, QN=512, D=QD=1024, H=QH=16, HD=64. fp32 in/out, bf16 MFMA.

#define AS1(p) ((const __attribute__((address_space(1))) void*)(p))
#define AS3(p) ((__attribute__((address_space(3))) void*)(p))
__device__ __forceinline__ void gl16(const void* g, void* l) {
    __builtin_amdgcn_global_load_lds(AS1(g), AS3(l), 16, 0, 0);
}
// raw barrier: ds-writes visible, but vmcnt prefetch stays in flight
#define SOFT_BARRIER() asm volatile("s_waitcnt lgkmcnt(0)\n\ts_barrier" ::: "memory")

// ---------------------------------------------------------------------------
// fp32 -> bf16 cast for x and query
// ---------------------------------------------------------------------------
__global__ __launch_bounds__(256) void cast_bf16(
    const float* __restrict__ s0, bf16* __restrict__ d0, int n0,
    const float* __restrict__ s1, bf16* __restrict__ d1, int n1)
{
    int idx = (blockIdx.x * 256 + threadIdx.x) << 3;
    const float* s; bf16* d;
    if (idx < n0) { s = s0 + idx; d = d0 + idx; }
    else { int k = idx - n0; if (k >= n1) return; s = s1 + k; d = d1 + k; }
    f32x4 a = *(const f32x4*)s, c = *(const f32x4*)(s + 4);
    bf16x8 v;
#pragma unroll
    for (int j = 0; j < 4; j++) { v[j] = (bf16)a[j]; v[4 + j] = (bf16)c[j]; }
    *(bf16x8*)d = v;
}

// ---------------------------------------------------------------------------
// Weights [1024][N] fp32 -> bf16 transposed [N][1024]
// ---------------------------------------------------------------------------
__global__ __launch_bounds__(256) void wtrans(
    const float* __restrict__ S0, bf16* __restrict__ D0,
    const float* __restrict__ S1, bf16* __restrict__ D1,
    const float* __restrict__ S2, bf16* __restrict__ D2,
    const float* __restrict__ S3, bf16* __restrict__ D3,
    const float* __restrict__ S4, bf16* __restrict__ D4)
{
    __shared__ float T[64][65];
    int gx = blockIdx.x, k0 = blockIdx.y << 6;
    const float* S; bf16* D; int N;
    if (gx < 48)       { S = S0; D = D0; N = 3072; }
    else if (gx < 80)  { S = S1; D = D1; N = 2048; gx -= 48; }
    else if (gx < 128) { S = S2; D = D2; N = 3072; gx -= 80; }
    else if (gx < 144) { S = S3; D = D3; N = 1024; gx -= 128; }
    else               { S = S4; D = D4; N = 1024; gx -= 144; }
    int n0 = gx << 6, tid = threadIdx.x;
#pragma unroll
    for (int rr = 0; rr < 4; rr++) {
        int row = (rr << 4) + (tid >> 4), col = (tid & 15) << 2;
        f32x4 v = *(const f32x4*)(S + (size_t)(k0 + row) * N + n0 + col);
#pragma unroll
        for (int j = 0; j < 4; j++) T[col + j][row] = v[j];
    }
    __syncthreads();
    {
        int n = tid >> 2, kc = (tid & 3) << 4;
        bf16x8 v0, v1;
#pragma unroll
        for (int j = 0; j < 8; j++) {
            v0[j] = (bf16)T[n][kc + j];
            v1[j] = (bf16)T[n][kc + 8 + j];
        }
        bf16* dp = D + (size_t)(n0 + n) * 1024 + k0 + kc;
        *(bf16x8*)dp = v0; *(bf16x8*)(dp + 8) = v1;
    }
}

// ---------------------------------------------------------------------------
// GEMM: C[M,N] = A[M,K] @ Bt[N,K]^T, 128x128 tile, BK=64, global_load_lds,
// XOR-swizzled LDS. SPLIT epilogue: each wave's 64x64 block is one
// (split s, head h) x 64 tokens; round-trip through LDS -> coalesced b128
// stores. s==0 output scaled by s0scale (pre-scales Q for attention).
// Last split (V) written transposed [bh][hd][ntok].
// ---------------------------------------------------------------------------
template <int NSPLIT, typename OT>
__global__ __launch_bounds__(256) void gemm_bt(
    const bf16* __restrict__ A, const bf16* __restrict__ Bt,
    OT* __restrict__ C0, OT* __restrict__ C1, OT* __restrict__ C2,
    const float* __restrict__ bias, int M, int N, int K, int tshift,
    float s0scale)
{
    __shared__ __align__(16) bf16 gsm[18432];   // As 8192 | Bs 8192 | pad; epilogue: 4x4608 per-wave
    bf16* As = gsm;
    bf16* Bs = gsm + 8192;

    const int tid = threadIdx.x;
    const int wave = tid >> 6, lane = tid & 63;
    const int l15 = lane & 15, g = lane >> 4;
    const int wr = wave & 1, wc = wave >> 1;
    const int m0 = blockIdx.y << 7, n0 = blockIdx.x << 7;

    int sr[4], sc[4];
#pragma unroll
    for (int i = 0; i < 4; i++) {
        int L = (i << 8) + tid;
        sr[i] = L >> 3;
        sc[i] = (L & 7) ^ (sr[i] & 7);
    }
    const int ldsbase = (tid & 192) << 4;

    f32x4 acc[4][4] = {};

    for (int k0 = 0; k0 < K; k0 += 64) {
        __syncthreads();
#pragma unroll
        for (int i = 0; i < 4; i++) {
            gl16(A  + (size_t)(m0 + sr[i]) * K + k0 + (sc[i] << 3),
                 (char*)As + (i << 12) + ldsbase);
            gl16(Bt + (size_t)(n0 + sr[i]) * K + k0 + (sc[i] << 3),
                 (char*)Bs + (i << 12) + ldsbase);
        }
        __syncthreads();

#pragma unroll
        for (int ks = 0; ks < 2; ks++) {
            bf16x8 af[4], bq[4];
#pragma unroll
            for (int mb = 0; mb < 4; mb++) {
                int row = (wr << 6) + (mb << 4) + l15;
                af[mb] = *(const bf16x8*)((const char*)As + (row << 7)
                          + ((((ks << 2) + g) ^ (row & 7)) << 4));
            }
#pragma unroll
            for (int nb = 0; nb < 4; nb++) {
                int row = (wc << 6) + (nb << 4) + l15;
                bq[nb] = *(const bf16x8*)((const char*)Bs + (row << 7)
                          + ((((ks << 2) + g) ^ (row & 7)) << 4));
            }
#pragma unroll
            for (int mb = 0; mb < 4; mb++)
#pragma unroll
                for (int nb = 0; nb < 4; nb++)
                    acc[mb][nb] = __builtin_amdgcn_mfma_f32_16x16x32_bf16(
                        af[mb], bq[nb], acc[mb][nb], 0, 0, 0);
        }
    }

    if constexpr (NSPLIT == 0) {
#pragma unroll
        for (int mb = 0; mb < 4; mb++)
#pragma unroll
            for (int nb = 0; nb < 4; nb++) {
                int n = n0 + (wc << 6) + (nb << 4) + l15;
                int mbase = m0 + (wr << 6) + (mb << 4) + (g << 2);
                float bi = bias[n];
#pragma unroll
                for (int r = 0; r < 4; r++)
                    C0[(size_t)(mbase + r) * N + n] = (OT)(acc[mb][nb][r] + bi);
            }
    } else {
        __syncthreads();
        bf16* stg = gsm + wave * 4608;
        const int nh = (n0 >> 6) + wc;
        const int sl = nh >> 4, hq = nh & 15;
        const float scl = (sl == 0) ? s0scale : 1.0f;
        const bool isv = (sl == NSPLIT - 1);
        if (isv) {   // stage transposed [hd][t], stride 72
#pragma unroll
            for (int mb = 0; mb < 4; mb++)
#pragma unroll
                for (int nb = 0; nb < 4; nb++)
#pragma unroll
                    for (int r = 0; r < 4; r++)
                        stg[((nb << 4) + l15) * 72 + (mb << 4) + (g << 2) + r]
                            = (bf16)(acc[mb][nb][r] * scl);
        } else {     // stage [t][hd], stride 64
#pragma unroll
            for (int mb = 0; mb < 4; mb++)
#pragma unroll
                for (int nb = 0; nb < 4; nb++)
#pragma unroll
                    for (int r = 0; r < 4; r++)
                        stg[((mb << 4) + (g << 2) + r) << 6 | ((nb << 4) + l15)]
                            = (bf16)(acc[mb][nb][r] * scl);
        }
        const int ntok = 1 << tshift;
        const int tok0 = m0 + (wr << 6);
        const int b = tok0 >> tshift, t0 = tok0 & (ntok - 1);
        const int bh_ = (b << 4) + hq;
        OT* dst = (sl == 0) ? C0 : (sl == 1) ? C1 : C2;
#pragma unroll
        for (int rr = 0; rr < 8; rr++) {
            int idx = (rr << 6) + lane;
            int rowi = idx >> 3, c = idx & 7;
            if (isv) {
                bf16x8 vv = *(const bf16x8*)&stg[rowi * 72 + (c << 3)];
                *(bf16x8*)&dst[((size_t)((bh_ << 6) + rowi)) * ntok + t0 + (c << 3)] = vv;
            } else {
                bf16x8 vv = *(const bf16x8*)&stg[(rowi << 6) + (c << 3)];
                *(bf16x8*)&dst[(((size_t)bh_ * ntok + t0 + rowi) << 6) + (c << 3)] = vv;
            }
        }
    }
}

// ---------------------------------------------------------------------------
// Flash attention, S^T form, fixed-max softmax (scores pre-scaled to log2
// domain via Q), register-prefetch double-buffered K/V staging with raw
// s_barrier (no vmcnt drain). Q [bh][nq][64] (pre-scaled), K [bh][nk][64],
// Vt [bh][64][nk]. Two flattened segments: seg0 weight tanh(gate[h]), seg1
// weight 1. O [b][nq][16*64].
// ---------------------------------------------------------------------------
__global__ __launch_bounds__(256, 4) void flash2(
    const bf16* __restrict__ Q,
    const bf16* __restrict__ K1, const bf16* __restrict__ V1t,
    const bf16* __restrict__ K2, const bf16* __restrict__ V2t,
    bf16* __restrict__ O, const float* __restrict__ gate,
    int nq, int nk1, int nk2)
{
    // buf b: K at b*8192, V at b*8192+4096; Ps at 16384 + wave*1024  (40960 B)
    __shared__ __align__(16) bf16 fsm[20480];

    const int tid = threadIdx.x;
    const int wave = tid >> 6, lane = tid & 63;
    const int l15 = lane & 15, g = lane >> 4;
    const int bh = blockIdx.y, h = bh & 15, b = bh >> 4;
    const int q0 = blockIdx.x << 6;
    const int T1 = nk1 >> 6, T2 = nk2 >> 6, T = T1 + T2;

    bf16* Psw = fsm + 16384 + (wave << 10);

    // Q fragments straight from global (B-operand: n=l15 -> q, k=ks*32+g*8+j)
    const bf16* qrow = Q + ((size_t)bh * nq + q0 + (wave << 4) + l15) * 64;
    bf16x8 qf[2];
    qf[0] = *(const bf16x8*)(qrow + (g << 3));
    qf[1] = *(const bf16x8*)(qrow + 32 + (g << 3));

    // staging geometry: 2 K-chunks + 2 V-chunks per thread per tile
    const int r0 = tid >> 3, c0 = tid & 7;
    const int swz = (c0 ^ (r0 & 7)) << 3;              // same for r0 and r0+32
    const int d0 = (r0 << 6) + swz, d1 = d0 + 2048;    // elem offsets in K/V region

    f32x4 Oacc[4] = {}, Ofin[4] = {};
    float lcur = 0.0f;
    const float gmul = gate ? tanhf(gate[h]) : 1.0f;

    auto loadt = [&](int t, bf16x8& ka, bf16x8& kb2, bf16x8& va, bf16x8& vb2) {
        const bf16 *kb, *vb; int stride;
        if (t < T1) {
            kb = K1 + ((size_t)bh * nk1 + (t << 6)) * 64;
            vb = V1t + (((size_t)bh << 6)) * nk1 + (t << 6);
            stride = nk1;
        } else {
            int u = t - T1;
            kb = K2 + ((size_t)bh * nk2 + (u << 6)) * 64;
            vb = V2t + (((size_t)bh << 6)) * nk2 + (u << 6);
            stride = nk2;
        }
        ka  = *(const bf16x8*)(kb + (r0 << 6) + (c0 << 3));
        kb2 = *(const bf16x8*)(kb + ((r0 + 32) << 6) + (c0 << 3));
        va  = *(const bf16x8*)(vb + (size_t)r0 * stride + (c0 << 3));
        vb2 = *(const bf16x8*)(vb + (size_t)(r0 + 32) * stride + (c0 << 3));
    };
    auto store_lds = [&](int bsel, bf16x8 ka, bf16x8 kb2, bf16x8 va, bf16x8 vb2) {
        bf16* Kb = fsm + (bsel << 13);
        bf16* Vb = Kb + 4096;
        *(bf16x8*)(Kb + d0) = ka;  *(bf16x8*)(Kb + d1) = kb2;
        *(bf16x8*)(Vb + d0) = va;  *(bf16x8*)(Vb + d1) = vb2;
    };
    auto compute = [&](int t, int bsel) {
        const bf16* Kb = fsm + (bsel << 13);
        const bf16* Vb = Kb + 4096;
        f32x4 S[4];
#pragma unroll
        for (int nb = 0; nb < 4; nb++) {
            f32x4 s = {};
#pragma unroll
            for (int ks = 0; ks < 2; ks++) {
                int row = (nb << 4) + l15;
                bf16x8 kf = *(const bf16x8*)(Kb + (row << 6)
                              + ((((ks << 2) + g) ^ (row & 7)) << 3));
                s = __builtin_amdgcn_mfma_f32_16x16x32_bf16(kf, qf[ks], s, 0, 0, 0);
            }
            S[nb] = s;
        }
        float rs = 0.0f;
#pragma unroll
        for (int nb = 0; nb < 4; nb++) {
            bf16x4 pv;
#pragma unroll
            for (int r = 0; r < 4; r++) {
                float p = exp2f(S[nb][r]);
                rs += p;
                pv[r] = (bf16)p;
            }
            *(bf16x4*)(Psw + (l15 << 6)
                + ((((nb << 1) + (g >> 1)) ^ (l15 & 7)) << 3) + ((g & 1) << 2)) = pv;
        }
        rs += __shfl_xor(rs, 16);
        rs += __shfl_xor(rs, 32);
        lcur += rs;
#pragma unroll
        for (int ks = 0; ks < 2; ks++) {
            bf16x8 pf = *(const bf16x8*)(Psw + (l15 << 6)
                          + ((((ks << 2) + g) ^ (l15 & 7)) << 3));
#pragma unroll
            for (int hb = 0; hb < 4; hb++) {
                int row = (hb << 4) + l15;
                bf16x8 vf = *(const bf16x8*)(Vb + (row << 6)
                              + ((((ks << 2) + g) ^ (row & 7)) << 3));
                Oacc[hb] = __builtin_amdgcn_mfma_f32_16x16x32_bf16(vf, pf, Oacc[hb], 0, 0, 0);
            }
        }
        if (t == T1 - 1 && T2 > 0) {   // segment boundary flush
            float w = gmul / lcur;
#pragma unroll
            for (int hb = 0; hb < 4; hb++)
#pragma unroll
                for (int r = 0; r < 4; r++) { Ofin[hb][r] += Oacc[hb][r] * w; Oacc[hb][r] = 0.0f; }
            lcur = 0.0f;
        }
    };

    bf16x8 ka0, ka1, vva0, vva1, kb0, kb1, vvb0, vvb1;
    loadt(0, ka0, ka1, vva0, vva1);
    for (int t = 0; t < T; t += 2) {
        if (t + 1 < T) loadt(t + 1, kb0, kb1, vvb0, vvb1);
        store_lds(0, ka0, ka1, vva0, vva1);
        SOFT_BARRIER();
        compute(t, 0);
        if (t + 1 >= T) break;
        if (t + 2 < T) loadt(t + 2, ka0, ka1, vva0, vva1);
        store_lds(1, kb0, kb1, vvb0, vvb1);
        SOFT_BARRIER();
        compute(t + 1, 1);
    }
    {   // final flush (seg1 weight 1, or whole thing gated if single-segment)
        float w = (T2 > 0 ? 1.0f : gmul) / lcur;
#pragma unroll
        for (int hb = 0; hb < 4; hb++)
#pragma unroll
            for (int r = 0; r < 4; r++) Ofin[hb][r] += Oacc[hb][r] * w;
    }

    // epilogue: O^T regs -> LDS [hd][q] (stride 72) -> coalesced O stores
    __syncthreads();
    bf16* OB = fsm;
#pragma unroll
    for (int hb = 0; hb < 4; hb++)
#pragma unroll
        for (int r = 0; r < 4; r++)
            OB[((hb << 4) + (g << 2) + r) * 72 + (wave << 4) + l15] = (bf16)Ofin[hb][r];
    __syncthreads();
    {
        int q = tid >> 2, quarter = (tid & 3) << 4;
        bf16x8 o0, o1;
#pragma unroll
        for (int j = 0; j < 8; j++) {
            o0[j] = OB[(quarter + j) * 72 + q];
            o1[j] = OB[(quarter + 8 + j) * 72 + q];
        }
        bf16* op = O + (((size_t)b * nq + q0 + q) << 10) + (h << 6) + quarter;
        *(bf16x8*)op = o0;
        *(bf16x8*)(op + 8) = o1;
    }
}

// ---------------------------------------------------------------------------
// lr_out[b,i,j] = sum_k low_res[b,(i*64+k)&255,(i*64+k)>>8] * W[k,j] + bias[j]
// ---------------------------------------------------------------------------
__global__ __launch_bounds__(256) void lr_kernel(
    const float* __restrict__ low_res, const float* __restrict__ W,
    const float* __restrict__ bias, float* __restrict__ out)
{
    int idx = blockIdx.x * 256 + threadIdx.x;
    int j = idx & 63, i = (idx >> 6) & 255, b = idx >> 14;
    float acc = bias[j];
    const float* lr = low_res + ((size_t)b << 14);
    for (int k = 0; k < 64; k++) {
        int f = i * 64 + k;
        acc += lr[((f & 255) << 6) + (f >> 8)] * W[(k << 6) + j];
    }
    out[idx] = acc;
}

// ---------------------------------------------------------------------------
extern "C" void kernel_launch(void* const* d_in, const int* in_sizes, int n_in,
                              void* d_out, int out_size, void* d_ws, size_t ws_size,
                              hipStream_t stream)
{
    const float* x       = (const float*)d_in[0];
    const float* query   = (const float*)d_in[1];
    const float* lowres  = (const float*)d_in[2];
    const float* W_qkv   = (const float*)d_in[3];
    const float* W_xkv   = (const float*)d_in[4];
    const float* W_qlin  = (const float*)d_in[5];
    const float* gate    = (const float*)d_in[6];
    const float* W_proj  = (const float*)d_in[7];
    const float* b_proj  = (const float*)d_in[8];
    const float* W_qproj = (const float*)d_in[9];
    const float* b_qproj = (const float*)d_in[10];
    const float* W_lr    = (const float*)d_in[11];
    const float* b_lr    = (const float*)d_in[12];
    float* out = (float*)d_out;

    const float sc2 = 0.125f * 1.44269504088896f;   // scale * log2(e), folded into Q

    char* ws = (char*)d_ws;
    bf16* Wtqkv   = (bf16*)ws; ws += 6291456;
    bf16* Wtxkv   = (bf16*)ws; ws += 4194304;
    bf16* Wtqlin  = (bf16*)ws; ws += 6291456;
    bf16* Wtproj  = (bf16*)ws; ws += 2097152;
    bf16* Wtqproj = (bf16*)ws; ws += 2097152;
    bf16* xb      = (bf16*)ws; ws += 8388608;   // ax aliases (xb dead by then)
    bf16* qryb    = (bf16*)ws; ws += 2097152;   // aq aliases
    bf16* qb      = (bf16*)ws; ws += 8388608;
    bf16* kb      = (bf16*)ws; ws += 8388608;
    bf16* vbt     = (bf16*)ws; ws += 8388608;   // [bh][64][2048]
    bf16* k2      = (bf16*)ws; ws += 8388608;
    bf16* v2t     = (bf16*)ws; ws += 8388608;   // [bh][64][2048]
    bf16* qq      = (bf16*)ws; ws += 2097152;
    bf16* qk      = (bf16*)ws; ws += 2097152;
    bf16* qvt     = (bf16*)ws; ws += 2097152;   // [bh][64][512]
    bf16* ax = xb;
    bf16* aq = qryb;

    cast_bf16<<<2560, 256, 0, stream>>>(x, xb, 4194304, query, qryb, 1048576);
    wtrans<<<dim3(160, 16), 256, 0, stream>>>(W_qkv, Wtqkv, W_xkv, Wtxkv,
                                              W_qlin, Wtqlin, W_proj, Wtproj,
                                              W_qproj, Wtqproj);

    gemm_bt<3, bf16><<<dim3(24, 32), 256, 0, stream>>>(
        xb, Wtqkv, qb, kb, vbt, nullptr, 4096, 3072, 1024, 11, sc2);
    gemm_bt<2, bf16><<<dim3(16, 32), 256, 0, stream>>>(
        xb, Wtxkv, k2, v2t, nullptr, nullptr, 4096, 2048, 1024, 11, 1.0f);
    gemm_bt<3, bf16><<<dim3(24, 8), 256, 0, stream>>>(
        qryb, Wtqlin, qq, qk, qvt, nullptr, 1024, 3072, 1024, 9, sc2);

    flash2<<<dim3(32, 32), 256, 0, stream>>>(
        qb, kb, vbt, nullptr, nullptr, ax, nullptr, 2048, 2048, 0);
    flash2<<<dim3(8, 32), 256, 0, stream>>>(
        qq, k2, v2t, qk, qvt, aq, gate, 512, 2048, 512);

    gemm_bt<0, float><<<dim3(8, 32), 256, 0, stream>>>(
        ax, Wtproj, out, nullptr, nullptr, b_proj, 4096, 1024, 1024, 0, 1.0f);
    gemm_bt<0, float><<<dim3(8, 8), 256, 0, stream>>>(
        aq, Wtqproj, out + 4194304, nullptr, nullptr, b_qproj, 1024, 1024, 1024, 0, 1.0f);
    lr_kernel<<<128, 256, 0, stream>>>(lowres, W_lr, b_lr, out + 5242880);

    (void)in_sizes; (void)n_in; (void)out_size; (void)ws_size;
}

// Round 6
// 352.507 us; speedup vs baseline: 1.8562x; 1.0700x over previous
//
#include <hip/hip_runtime.h>

typedef __bf16 bf16;
typedef __bf16 bf16x4 __attribute__((ext_vector_type(4)));
typedef __bf16 bf16x8 __attribute__((ext_vector_type(8)));
typedef float  f32x4  __attribute__((ext_vector_type(4)));

// B=2, N=2048, QN=512, D=QD=1024, H=QH=16, HD=64. fp32 in/out, bf16 MFMA.

#define AS1(p) ((const __attribute__((address_space(1))) void*)(p))
#define AS3(p) ((__attribute__((address_space(3))) void*)(p))
__device__ __forceinline__ void gl16(const void* g, void* l) {
    __builtin_amdgcn_global_load_lds(AS1(g), AS3(l), 16, 0, 0);
}
// soft barriers: per-wave bounded vmcnt wait; prefetch loads stay in flight.
#define BAR_VM4() asm volatile("s_waitcnt vmcnt(4)\n\ts_barrier" ::: "memory")
#define BAR_VM0() asm volatile("s_waitcnt vmcnt(0)\n\ts_barrier" ::: "memory")
#define BAR()     asm volatile("s_barrier" ::: "memory")

// ---------------------------------------------------------------------------
// fp32 -> bf16 cast for x and query
// ---------------------------------------------------------------------------
__global__ __launch_bounds__(256) void cast_bf16(
    const float* __restrict__ s0, bf16* __restrict__ d0, int n0,
    const float* __restrict__ s1, bf16* __restrict__ d1, int n1)
{
    int idx = (blockIdx.x * 256 + threadIdx.x) << 3;
    const float* s; bf16* d;
    if (idx < n0) { s = s0 + idx; d = d0 + idx; }
    else { int k = idx - n0; if (k >= n1) return; s = s1 + k; d = d1 + k; }
    f32x4 a = *(const f32x4*)s, c = *(const f32x4*)(s + 4);
    bf16x8 v;
#pragma unroll
    for (int j = 0; j < 4; j++) { v[j] = (bf16)a[j]; v[4 + j] = (bf16)c[j]; }
    *(bf16x8*)d = v;
}

// ---------------------------------------------------------------------------
// Weights [1024][N] fp32 -> bf16 transposed [N][1024]
// ---------------------------------------------------------------------------
__global__ __launch_bounds__(256) void wtrans(
    const float* __restrict__ S0, bf16* __restrict__ D0,
    const float* __restrict__ S1, bf16* __restrict__ D1,
    const float* __restrict__ S2, bf16* __restrict__ D2,
    const float* __restrict__ S3, bf16* __restrict__ D3,
    const float* __restrict__ S4, bf16* __restrict__ D4)
{
    __shared__ float T[64][65];
    int gx = blockIdx.x, k0 = blockIdx.y << 6;
    const float* S; bf16* D; int N;
    if (gx < 48)       { S = S0; D = D0; N = 3072; }
    else if (gx < 80)  { S = S1; D = D1; N = 2048; gx -= 48; }
    else if (gx < 128) { S = S2; D = D2; N = 3072; gx -= 80; }
    else if (gx < 144) { S = S3; D = D3; N = 1024; gx -= 128; }
    else               { S = S4; D = D4; N = 1024; gx -= 144; }
    int n0 = gx << 6, tid = threadIdx.x;
#pragma unroll
    for (int rr = 0; rr < 4; rr++) {
        int row = (rr << 4) + (tid >> 4), col = (tid & 15) << 2;
        f32x4 v = *(const f32x4*)(S + (size_t)(k0 + row) * N + n0 + col);
#pragma unroll
        for (int j = 0; j < 4; j++) T[col + j][row] = v[j];
    }
    __syncthreads();
    {
        int n = tid >> 2, kc = (tid & 3) << 4;
        bf16x8 v0, v1;
#pragma unroll
        for (int j = 0; j < 8; j++) {
            v0[j] = (bf16)T[n][kc + j];
            v1[j] = (bf16)T[n][kc + 8 + j];
        }
        bf16* dp = D + (size_t)(n0 + n) * 1024 + k0 + kc;
        *(bf16x8*)dp = v0; *(bf16x8*)(dp + 8) = v1;
    }
}

// ---------------------------------------------------------------------------
// GEMM: C[M,N] = A[M,K] @ Bt[N,K]^T, 128x128 tile, BK=32, LDS double-buffered
// global_load_lds staging, soft barriers (vmcnt(4), never drained).
// LDS swizzle: slot s of row r holds chunk s ^ ((r^(r>>2))&3)  (2-way, free).
// NSPLIT>0: epilogue scatters 64-col head-blocks into per-head buffers via
// LDS round-trip; vmask bit per split = write transposed [bh][hd][ntok].
// s0scale multiplies split 0 (pre-scales Q for attention).
// ---------------------------------------------------------------------------
template <int NSPLIT, typename OT>
__global__ __launch_bounds__(256) void gemm_bt(
    const bf16* __restrict__ A, const bf16* __restrict__ Bt,
    OT* __restrict__ C0, OT* __restrict__ C1, OT* __restrict__ C2,
    OT* __restrict__ C3, OT* __restrict__ C4,
    const float* __restrict__ bias, int M, int N, int K, int tshift,
    float s0scale, unsigned vmask)
{
    __shared__ __align__(16) bf16 gsm[18432];   // bufs: 2x16KB; epilogue: 4x4608

    const int tid  = threadIdx.x;
    const int wave = tid >> 6, lane = tid & 63;
    const int l15  = lane & 15, g = lane >> 4;
    const int wr   = wave & 1, wc = wave >> 1;
    const int m0   = blockIdx.y << 7, n0 = blockIdx.x << 7;

    f32x4 acc[4][4] = {};

    auto stage = [&](int t, int bsel) {
        const bf16* Ab = A  + (size_t)m0 * K + (t << 5);
        const bf16* Bb = Bt + (size_t)n0 * K + (t << 5);
        char* Ad = (char*)gsm + (bsel << 14);
        char* Bd = Ad + 8192;
        const int wb = (tid & 192) << 4;
#pragma unroll
        for (int i = 0; i < 2; i++) {
            int L = (i << 8) + tid;
            int r = L >> 2, c = (L & 3) ^ ((r ^ (r >> 2)) & 3);
            gl16(Ab + (size_t)r * K + (c << 3), Ad + (i << 12) + wb);
            gl16(Bb + (size_t)r * K + (c << 3), Bd + (i << 12) + wb);
        }
    };
    auto compute = [&](int bsel) {
        const char* Ad = (const char*)gsm + (bsel << 14);
        const char* Bd = Ad + 8192;
        bf16x8 af[4], bq[4];
#pragma unroll
        for (int mb = 0; mb < 4; mb++) {
            int row = (wr << 6) + (mb << 4) + l15;
            af[mb] = *(const bf16x8*)(Ad + (row << 6)
                      + ((g ^ ((row ^ (row >> 2)) & 3)) << 4));
        }
#pragma unroll
        for (int nb = 0; nb < 4; nb++) {
            int row = (wc << 6) + (nb << 4) + l15;
            bq[nb] = *(const bf16x8*)(Bd + (row << 6)
                      + ((g ^ ((row ^ (row >> 2)) & 3)) << 4));
        }
#pragma unroll
        for (int mb = 0; mb < 4; mb++)
#pragma unroll
            for (int nb = 0; nb < 4; nb++)
                acc[mb][nb] = __builtin_amdgcn_mfma_f32_16x16x32_bf16(
                    af[mb], bq[nb], acc[mb][nb], 0, 0, 0);
    };

    const int T = K >> 5;
    stage(0, 0);
    for (int t = 0; t < T; t++) {
        int bsel = t & 1;
        if (t + 1 < T) { stage(t + 1, bsel ^ 1); BAR_VM4(); }
        else           { BAR_VM0(); }
        compute(bsel);
        BAR();
    }

    if constexpr (NSPLIT == 0) {
#pragma unroll
        for (int mb = 0; mb < 4; mb++)
#pragma unroll
            for (int nb = 0; nb < 4; nb++) {
                int n = n0 + (wc << 6) + (nb << 4) + l15;
                int mbase = m0 + (wr << 6) + (mb << 4) + (g << 2);
                float bi = bias[n];
#pragma unroll
                for (int r = 0; r < 4; r++)
                    C0[(size_t)(mbase + r) * N + n] = (OT)(acc[mb][nb][r] + bi);
            }
    } else {
        BAR();
        bf16* stg = gsm + wave * 4608;
        const int nh = (n0 >> 6) + wc;
        const int sl = nh >> 4, hq = nh & 15;
        const float scl = (sl == 0) ? s0scale : 1.0f;
        const bool isv = (vmask >> sl) & 1;
        if (isv) {   // stage transposed [hd][t], stride 72
#pragma unroll
            for (int mb = 0; mb < 4; mb++)
#pragma unroll
                for (int nb = 0; nb < 4; nb++)
#pragma unroll
                    for (int r = 0; r < 4; r++)
                        stg[((nb << 4) + l15) * 72 + (mb << 4) + (g << 2) + r]
                            = (bf16)(acc[mb][nb][r] * scl);
        } else {     // stage [t][hd], stride 64
#pragma unroll
            for (int mb = 0; mb < 4; mb++)
#pragma unroll
                for (int nb = 0; nb < 4; nb++)
#pragma unroll
                    for (int r = 0; r < 4; r++)
                        stg[((mb << 4) + (g << 2) + r) << 6 | ((nb << 4) + l15)]
                            = (bf16)(acc[mb][nb][r] * scl);
        }
        __syncthreads();
        const int ntok = 1 << tshift;
        const int tok0 = m0 + (wr << 6);
        const int b = tok0 >> tshift, t0 = tok0 & (ntok - 1);
        const int bh_ = (b << 4) + hq;
        OT* dst = (sl == 0) ? C0 : (sl == 1) ? C1 : (sl == 2) ? C2
                : (sl == 3) ? C3 : C4;
#pragma unroll
        for (int rr = 0; rr < 8; rr++) {
            int idx = (rr << 6) + lane;
            int rowi = idx >> 3, c = idx & 7;
            if (isv) {
                bf16x8 vv = *(const bf16x8*)&stg[rowi * 72 + (c << 3)];
                *(bf16x8*)&dst[((size_t)((bh_ << 6) + rowi)) * ntok + t0 + (c << 3)] = vv;
            } else {
                bf16x8 vv = *(const bf16x8*)&stg[(rowi << 6) + (c << 3)];
                *(bf16x8*)&dst[(((size_t)bh_ * ntok + t0 + rowi) << 6) + (c << 3)] = vv;
            }
        }
    }
}

// ---------------------------------------------------------------------------
// Flash attention, S^T form, q-tile 128, fixed-max softmax (Q pre-scaled to
// log2 domain), double-buffered global_load_lds K/V staging, soft barriers.
// Q [bh][nq][64], K [bh][nk][64], Vt [bh][64][nk]. NSEG=2: seg0 (K1/V1t)
// weighted tanh(gate[h]), seg1 weight 1. O [b][nq][16*64].
// ---------------------------------------------------------------------------
template <int NSEG>
__global__ __launch_bounds__(256) void flash3(
    const bf16* __restrict__ Q,
    const bf16* __restrict__ K1, const bf16* __restrict__ V1t,
    const bf16* __restrict__ K2, const bf16* __restrict__ V2t,
    bf16* __restrict__ O, const float* __restrict__ gate,
    int nq, int nk1, int nk2)
{
    // bytes: K bufs [0,16384), V bufs [16384,32768), Ps [32768,49152)
    __shared__ __align__(16) bf16 fsm[24576];

    const int tid = threadIdx.x;
    const int wave = tid >> 6, lane = tid & 63;
    const int l15 = lane & 15, g = lane >> 4;
    const int bh = blockIdx.y, h = bh & 15, b = bh >> 4;
    const int q0 = blockIdx.x << 7;
    const int T1 = nk1 >> 6, T2 = (NSEG == 2) ? (nk2 >> 6) : 0, T = T1 + T2;
    const int swzP = (l15 ^ (l15 >> 3)) & 7;

    char* Psw = (char*)fsm + 32768 + (wave << 12);

    // Q frags straight from global: B-operand, n=l15 (q), k=ks*32+g*8+j
    bf16x8 qf[2][2];
#pragma unroll
    for (int qb = 0; qb < 2; qb++) {
        const bf16* qrow = Q + ((size_t)bh * nq + q0 + (wave << 5) + (qb << 4) + l15) * 64;
        qf[qb][0] = *(const bf16x8*)(qrow + (g << 3));
        qf[qb][1] = *(const bf16x8*)(qrow + 32 + (g << 3));
    }

    f32x4 Oacc[4][2] = {}, Ofin[4][2] = {};
    float lcur[2] = {0.0f, 0.0f};
    const float gmul = gate ? tanhf(gate[h]) : 1.0f;

    auto stage = [&](int t, int bsel) {
        const bf16 *kb, *vb; int stride;
        if (NSEG == 1 || t < T1) {
            kb = K1 + ((size_t)bh * nk1 + (t << 6)) * 64;
            vb = V1t + ((size_t)bh << 6) * nk1 + (t << 6);
            stride = nk1;
        } else {
            int u = t - T1;
            kb = K2 + ((size_t)bh * nk2 + (u << 6)) * 64;
            vb = V2t + ((size_t)bh << 6) * nk2 + (u << 6);
            stride = nk2;
        }
        char* Kd = (char*)fsm + (bsel << 13);
        char* Vd = (char*)fsm + 16384 + (bsel << 13);
        const int wb = (tid & 192) << 4;
#pragma unroll
        for (int i = 0; i < 2; i++) {
            int L = (i << 8) + tid;
            int r = L >> 3, c = (L & 7) ^ (r & 7);
            gl16(kb + (r << 6) + (c << 3),        Kd + (i << 12) + wb);
            gl16(vb + (size_t)r * stride + (c << 3), Vd + (i << 12) + wb);
        }
    };

    auto compute = [&](int t, int bsel) {
        const char* Kb = (const char*)fsm + (bsel << 13);
        const char* Vb = (const char*)fsm + 16384 + (bsel << 13);
        // S^T = K Q^T : 16 MFMAs
        f32x4 S[4][2];
#pragma unroll
        for (int nb = 0; nb < 4; nb++) {
            int row = (nb << 4) + l15;
            bf16x8 kf0 = *(const bf16x8*)(Kb + (row << 7) + ((g ^ (row & 7)) << 4));
            bf16x8 kf1 = *(const bf16x8*)(Kb + (row << 7) + (((4 + g) ^ (row & 7)) << 4));
#pragma unroll
            for (int qb = 0; qb < 2; qb++) {
                f32x4 s = {};
                s = __builtin_amdgcn_mfma_f32_16x16x32_bf16(kf0, qf[qb][0], s, 0, 0, 0);
                s = __builtin_amdgcn_mfma_f32_16x16x32_bf16(kf1, qf[qb][1], s, 0, 0, 0);
                S[nb][qb] = s;
            }
        }
        // exp2 + P store (P^T layout [q][k], swizzled) + row sums
        float rs[2] = {0.0f, 0.0f};
#pragma unroll
        for (int qb = 0; qb < 2; qb++)
#pragma unroll
            for (int nb = 0; nb < 4; nb++) {
                bf16x4 pv;
#pragma unroll
                for (int r = 0; r < 4; r++) {
                    float p = exp2f(S[nb][qb][r]);
                    rs[qb] += p;
                    pv[r] = (bf16)p;
                }
                *(bf16x4*)(Psw + (((qb << 4) + l15) << 7)
                    + ((((nb << 1) + (g >> 1)) ^ swzP) << 4) + ((g & 1) << 3)) = pv;
            }
#pragma unroll
        for (int qb = 0; qb < 2; qb++) {
            rs[qb] += __shfl_xor(rs[qb], 16);
            rs[qb] += __shfl_xor(rs[qb], 32);
            lcur[qb] += rs[qb];
        }
        // O^T += Vt @ P^T : 16 MFMAs
        bf16x8 pf[2][2];
#pragma unroll
        for (int qb = 0; qb < 2; qb++)
#pragma unroll
            for (int ks = 0; ks < 2; ks++)
                pf[qb][ks] = *(const bf16x8*)(Psw + (((qb << 4) + l15) << 7)
                              + ((((ks << 2) + g) ^ swzP) << 4));
#pragma unroll
        for (int hb = 0; hb < 4; hb++) {
            int row = (hb << 4) + l15;
            bf16x8 vf0 = *(const bf16x8*)(Vb + (row << 7) + ((g ^ (row & 7)) << 4));
            bf16x8 vf1 = *(const bf16x8*)(Vb + (row << 7) + (((4 + g) ^ (row & 7)) << 4));
#pragma unroll
            for (int qb = 0; qb < 2; qb++) {
                Oacc[hb][qb] = __builtin_amdgcn_mfma_f32_16x16x32_bf16(vf0, pf[qb][0], Oacc[hb][qb], 0, 0, 0);
                Oacc[hb][qb] = __builtin_amdgcn_mfma_f32_16x16x32_bf16(vf1, pf[qb][1], Oacc[hb][qb], 0, 0, 0);
            }
        }
        if (NSEG == 2 && t == T1 - 1) {   // gated-segment flush
#pragma unroll
            for (int qb = 0; qb < 2; qb++) {
                float w = gmul / lcur[qb];
#pragma unroll
                for (int hb = 0; hb < 4; hb++)
#pragma unroll
                    for (int r = 0; r < 4; r++) {
                        Ofin[hb][qb][r] += Oacc[hb][qb][r] * w;
                        Oacc[hb][qb][r] = 0.0f;
                    }
                lcur[qb] = 0.0f;
            }
        }
    };

    stage(0, 0);
    for (int t = 0; t < T; t++) {
        int bsel = t & 1;
        if (t + 1 < T) { stage(t + 1, bsel ^ 1); BAR_VM4(); }
        else           { BAR_VM0(); }
        compute(t, bsel);
        BAR();
    }

    // final weights
    float wfin[2];
#pragma unroll
    for (int qb = 0; qb < 2; qb++)
        wfin[qb] = (NSEG == 2 ? 1.0f : gmul) / lcur[qb];

    // epilogue: O^T regs -> LDS [hd=64][q=128] stride 136 -> coalesced stores
    bf16* OB = fsm;
#pragma unroll
    for (int hb = 0; hb < 4; hb++)
#pragma unroll
        for (int qb = 0; qb < 2; qb++)
#pragma unroll
            for (int r = 0; r < 4; r++) {
                float v = Oacc[hb][qb][r] * wfin[qb];
                if (NSEG == 2) v += Ofin[hb][qb][r];
                OB[((hb << 4) + (g << 2) + r) * 136 + (wave << 5) + (qb << 4) + l15] = (bf16)v;
            }
    __syncthreads();
    {
        int q = tid >> 1, half = (tid & 1) << 5;
        bf16x8 o[4];
#pragma unroll
        for (int j2 = 0; j2 < 4; j2++)
#pragma unroll
            for (int j = 0; j < 8; j++)
                o[j2][j] = OB[(half + (j2 << 3) + j) * 136 + q];
        bf16* op = O + (((size_t)b * nq + q0 + q) << 10) + (h << 6) + half;
#pragma unroll
        for (int j2 = 0; j2 < 4; j2++)
            *(bf16x8*)(op + (j2 << 3)) = o[j2];
    }
}

// ---------------------------------------------------------------------------
// lr_out[b,i,j] = sum_k low_res[b,(i*64+k)&255,(i*64+k)>>8] * W[k,j] + bias[j]
// ---------------------------------------------------------------------------
__global__ __launch_bounds__(256) void lr_kernel(
    const float* __restrict__ low_res, const float* __restrict__ W,
    const float* __restrict__ bias, float* __restrict__ out)
{
    int idx = blockIdx.x * 256 + threadIdx.x;
    int j = idx & 63, i = (idx >> 6) & 255, b = idx >> 14;
    float acc = bias[j];
    const float* lr = low_res + ((size_t)b << 14);
    for (int k = 0; k < 64; k++) {
        int f = i * 64 + k;
        acc += lr[((f & 255) << 6) + (f >> 8)] * W[(k << 6) + j];
    }
    out[idx] = acc;
}

// ---------------------------------------------------------------------------
extern "C" void kernel_launch(void* const* d_in, const int* in_sizes, int n_in,
                              void* d_out, int out_size, void* d_ws, size_t ws_size,
                              hipStream_t stream)
{
    const float* x       = (const float*)d_in[0];
    const float* query   = (const float*)d_in[1];
    const float* lowres  = (const float*)d_in[2];
    const float* W_qkv   = (const float*)d_in[3];
    const float* W_xkv   = (const float*)d_in[4];
    const float* W_qlin  = (const float*)d_in[5];
    const float* gate    = (const float*)d_in[6];
    const float* W_proj  = (const float*)d_in[7];
    const float* b_proj  = (const float*)d_in[8];
    const float* W_qproj = (const float*)d_in[9];
    const float* b_qproj = (const float*)d_in[10];
    const float* W_lr    = (const float*)d_in[11];
    const float* b_lr    = (const float*)d_in[12];
    float* out = (float*)d_out;

    const float sc2 = 0.125f * 1.44269504088896f;   // scale*log2e, folded into Q

    char* ws = (char*)d_ws;
    bf16* WtX     = (bf16*)ws; ws += 10485760;  // [5120][1024] = qkv|xkv transposed
    bf16* Wtqlin  = (bf16*)ws; ws += 6291456;
    bf16* Wtproj  = (bf16*)ws; ws += 2097152;
    bf16* Wtqproj = (bf16*)ws; ws += 2097152;
    bf16* xb      = (bf16*)ws; ws += 8388608;   // ax aliases (xb dead by then)
    bf16* qryb    = (bf16*)ws; ws += 2097152;   // aq aliases
    bf16* qb      = (bf16*)ws; ws += 8388608;
    bf16* kb      = (bf16*)ws; ws += 8388608;
    bf16* vbt     = (bf16*)ws; ws += 8388608;   // [bh][64][2048]
    bf16* k2      = (bf16*)ws; ws += 8388608;
    bf16* v2t     = (bf16*)ws; ws += 8388608;   // [bh][64][2048]
    bf16* qq      = (bf16*)ws; ws += 2097152;
    bf16* qk      = (bf16*)ws; ws += 2097152;
    bf16* qvt     = (bf16*)ws; ws += 2097152;   // [bh][64][512]
    bf16* ax = xb;
    bf16* aq = qryb;

    cast_bf16<<<2560, 256, 0, stream>>>(x, xb, 4194304, query, qryb, 1048576);
    wtrans<<<dim3(160, 16), 256, 0, stream>>>(
        W_qkv, WtX, W_xkv, WtX + (size_t)3072 * 1024,
        W_qlin, Wtqlin, W_proj, Wtproj, W_qproj, Wtqproj);

    // x @ [W_qkv | W_xkv] -> q,k,v,k2,v2 in one pass (v, v2 transposed)
    gemm_bt<5, bf16><<<dim3(40, 32), 256, 0, stream>>>(
        xb, WtX, qb, kb, vbt, k2, v2t, nullptr, 4096, 5120, 1024, 11, sc2, 0b10100u);
    // query @ W_qlin -> qq,qk,qv (qv transposed)
    gemm_bt<3, bf16><<<dim3(24, 8), 256, 0, stream>>>(
        qryb, Wtqlin, qq, qk, qvt, nullptr, nullptr, nullptr, 1024, 3072, 1024, 9, sc2, 0b100u);

    // self-attention over x
    flash3<1><<<dim3(16, 32), 256, 0, stream>>>(
        qb, kb, vbt, nullptr, nullptr, ax, nullptr, 2048, 2048, 0);
    // cross-attention: gated x-KV segment + plain query-KV segment
    flash3<2><<<dim3(4, 32), 256, 0, stream>>>(
        qq, k2, v2t, qk, qvt, aq, gate, 512, 2048, 512);

    gemm_bt<0, float><<<dim3(8, 32), 256, 0, stream>>>(
        ax, Wtproj, out, nullptr, nullptr, nullptr, nullptr, b_proj,
        4096, 1024, 1024, 0, 1.0f, 0u);
    gemm_bt<0, float><<<dim3(8, 8), 256, 0, stream>>>(
        aq, Wtqproj, out + 4194304, nullptr, nullptr, nullptr, nullptr, b_qproj,
        1024, 1024, 1024, 0, 1.0f, 0u);
    lr_kernel<<<128, 256, 0, stream>>>(lowres, W_lr, b_lr, out + 5242880);

    (void)in_sizes; (void)n_in; (void)out_size; (void)ws_size;
}